// Round 20
// baseline (1422.648 us; speedup 1.0000x reference)
//
#include <hip/hip_runtime.h>
#include <stdint.h>
#include <stddef.h>

// Problem dims
#define Bn   64
#define Tn   512
#define DINn 512
#define Hn   1024
#define OUTn 128

typedef __attribute__((ext_vector_type(4))) float f32x4;
typedef __attribute__((ext_vector_type(8))) short short8;
typedef __attribute__((ext_vector_type(4))) unsigned int u32x4;

__device__ __forceinline__ unsigned short f2bf(float f){
  unsigned int x = __builtin_bit_cast(unsigned int, f);
  x += 0x7fffu + ((x >> 16) & 1u);           // RNE (values bounded, no NaN/inf)
  return (unsigned short)(x >> 16);
}
__device__ __forceinline__ float bf2f(unsigned short u){
  return __builtin_bit_cast(float, (unsigned int)u << 16);
}
__device__ __forceinline__ float tanh_fast(float v){
  float e = __expf(2.0f * v);
  return 1.0f - 2.0f / (e + 1.0f);
}

// ---- protocol primitives ----
// MODE 0 (NT, r19-proven): XCD-local flags, per-wave detect + per-wave publish.
//   r20: 4 waves/wg, each owns a tile PAIR over full K (A-reuse halves LDS reads).
//   Flag word = slot*4 + w; consumer wave w's two producer wgs (2w,2w+1) = one 8-word line.
// MODE 1 (ATOM): r9-proven MALL atomics. MODE 2 (MALL): r4-proven sc0 sc1.
template<bool FAST>
__device__ __forceinline__ void st16(unsigned short* p, u32x4 v){
  if constexpr (FAST)
    asm volatile("global_store_dwordx4 %0, %1, off sc0" :: "v"(p), "v"(v) : "memory");
  else
    asm volatile("global_store_dwordx4 %0, %1, off sc0 sc1" :: "v"(p), "v"(v) : "memory");
}
__device__ __forceinline__ unsigned atom_poll(unsigned int* p){
  unsigned old, zero = 0;
  asm volatile("global_atomic_add %0, %1, %2, off sc0\n\t"
               "s_waitcnt vmcnt(0)"
               : "=&v"(old) : "v"(p), "v"(zero) : "memory");
  return old;
}
__device__ __forceinline__ void atom_poll2(unsigned int* p1, unsigned int* p2,
                                           unsigned &v1, unsigned &v2){
  unsigned zero = 0;
  asm volatile("global_atomic_add %0, %2, %4, off sc0\n\t"
               "global_atomic_add %1, %3, %4, off sc0\n\t"
               "s_waitcnt vmcnt(0)"
               : "=&v"(v1), "=&v"(v2)
               : "v"(p1), "v"(p2), "v"(zero) : "memory");
}
__device__ __forceinline__ void atom_inc(unsigned int* p){
  unsigned one = 1;
  asm volatile("global_atomic_add %0, %1, off" :: "v"(p), "v"(one) : "memory");
}
__device__ __forceinline__ unsigned ld1_sc0(const unsigned int* p){
  unsigned v;
  asm volatile("global_load_dword %0, %1, off sc0\n\t"
               "s_waitcnt vmcnt(0)" : "=&v"(v) : "v"(p) : "memory");
  return v;
}
__device__ __forceinline__ unsigned ld1_nt(const unsigned int* p){
  unsigned v;
  asm volatile("global_load_dword %0, %1, off nt\n\t"
               "s_waitcnt vmcnt(0)" : "=&v"(v) : "v"(p) : "memory");
  return v;
}
__device__ __forceinline__ unsigned umin4(u32x4 a){
  unsigned m0 = a[0] < a[1] ? a[0] : a[1];
  unsigned m1 = a[2] < a[3] ? a[2] : a[3];
  return m0 < m1 ? m0 : m1;
}
__device__ __forceinline__ unsigned ld_line8_nt(const unsigned int* p){
  u32x4 a, b;
  asm volatile("global_load_dwordx4 %0, %2, off nt\n\t"
               "global_load_dwordx4 %1, %3, off nt\n\t"
               "s_waitcnt vmcnt(0)"
               : "=&v"(a), "=&v"(b) : "v"(p), "v"(p + 4) : "memory");
  unsigned ma = umin4(a), mb = umin4(b);
  return ma < mb ? ma : mb;
}
__device__ __forceinline__ unsigned ld_line8_slow(const unsigned int* p){
  u32x4 a, b;
  asm volatile("global_load_dwordx4 %0, %2, off sc0 sc1\n\t"
               "global_load_dwordx4 %1, %3, off sc0 sc1\n\t"
               "s_waitcnt vmcnt(0)"
               : "=&v"(a), "=&v"(b) : "v"(p), "v"(p + 4) : "memory");
  unsigned ma = umin4(a), mb = umin4(b);
  return ma < mb ? ma : mb;
}
// Bounded waits. Worst case returns late -> visibly wrong, never a hang.
__device__ __forceinline__ void waitw_nt(const unsigned int* p, unsigned want){
  if (!want) return;
  for (int i = 0; i < (1 << 16); ++i){
    if (ld1_nt(p) >= want) return;
    if (i > 16) __builtin_amdgcn_s_sleep(1);
  }
}
__device__ __forceinline__ void wait8_nt(const unsigned int* p, unsigned want){
  if (!want) return;
  for (int i = 0; i < (1 << 16); ++i){
    if (ld_line8_nt(p) >= want) return;
    if (i > 16) __builtin_amdgcn_s_sleep(1);
  }
}
// role2 combined wait: min over 8-word line (h2 self-dep) AND single word (pre1 dep).
__device__ __forceinline__ void waitC_nt(const unsigned int* pline, unsigned wline,
                                         const unsigned int* pw, unsigned ww){
  for (int i = 0; i < (1 << 16); ++i){
    u32x4 a, b; unsigned v;
    asm volatile("global_load_dwordx4 %0, %3, off nt\n\t"
                 "global_load_dwordx4 %1, %4, off nt\n\t"
                 "global_load_dword %2, %5, off nt\n\t"
                 "s_waitcnt vmcnt(0)"
                 : "=&v"(a), "=&v"(b), "=&v"(v)
                 : "v"(pline), "v"(pline + 4), "v"(pw) : "memory");
    unsigned m = umin4(a) < umin4(b) ? umin4(a) : umin4(b);
    if (m >= wline && v >= ww) return;
    if (i > 16) __builtin_amdgcn_s_sleep(1);
  }
}
template<bool FAST>
__device__ __forceinline__ void wait_one(unsigned int* fc, unsigned int* fl, unsigned wfast, unsigned wslow){
  if constexpr (FAST){
    if (!wfast) return;
    for (int i = 0; i < (1 << 16); ++i){
      if (atom_poll(fc) >= wfast) return;
      if (i > 8) __builtin_amdgcn_s_sleep(1);
    }
  } else {
    if (!wslow) return;
    for (int i = 0; i < (1 << 16); ++i){
      if (ld_line8_slow(fl) >= wslow) return;
      if (i > 16) __builtin_amdgcn_s_sleep(1);
    }
  }
}
template<bool FAST>
__device__ __forceinline__ void wait_dual(unsigned int* fc1, unsigned int* fl1, unsigned wf1, unsigned ws1,
                                          unsigned int* fc2, unsigned int* fl2, unsigned wf2, unsigned ws2){
  if constexpr (FAST){
    if (!wf2){ wait_one<true>(fc1, fl1, wf1, ws1); return; }
    for (int i = 0; i < (1 << 16); ++i){
      unsigned v1, v2;
      atom_poll2(fc1, fc2, v1, v2);
      if (v1 >= wf1 && v2 >= wf2) return;
      if (i > 8) __builtin_amdgcn_s_sleep(1);
    }
  } else {
    if (!ws2){ wait_one<false>(fc1, fl1, wf1, ws1); return; }
    for (int i = 0; i < (1 << 16); ++i){
      if (ld_line8_slow(fl1) >= ws1 && ld_line8_slow(fl2) >= ws2) return;
      if (i > 16) __builtin_amdgcn_s_sleep(1);
    }
  }
}

// Per-wave 4KB (2-slice) copy global->LDS (lane-parallel, sc0, one drain).
__device__ __forceinline__ void stage_pw4k(const unsigned short* src, unsigned short* dst, int lane){
  const unsigned short* p0 = src + lane*8;
  u32x4 v0, v1, v2, v3;
  asm volatile("global_load_dwordx4 %0, %4, off sc0\n\t"
               "global_load_dwordx4 %1, %5, off sc0\n\t"
               "global_load_dwordx4 %2, %6, off sc0\n\t"
               "global_load_dwordx4 %3, %7, off sc0\n\t"
               "s_waitcnt vmcnt(0)"
               : "=&v"(v0), "=&v"(v1), "=&v"(v2), "=&v"(v3)
               : "v"(p0), "v"(p0 + 512), "v"(p0 + 1024), "v"(p0 + 1536) : "memory");
  *(u32x4*)(dst + lane*8) = v0;
  *(u32x4*)(dst + lane*8 + 512) = v1;
  *(u32x4*)(dst + lane*8 + 1024) = v2;
  *(u32x4*)(dst + lane*8 + 1536) = v3;
}
// Per-wave 4KB + 8 bf16 pv loads (2 tiles x 4 rows), one drain.
__device__ __forceinline__ void stage_pw4k_pv(const unsigned short* src, unsigned short* dst, int lane,
                                              const unsigned short* pA, const unsigned short* pB,
                                              float* pvA, float* pvB){
  const unsigned short* p0 = src + lane*8;
  u32x4 v0, v1, v2, v3;
  unsigned a0,a1,a2,a3,b0,b1,b2,b3;
  asm volatile(
    "global_load_dwordx4 %0, %12, off sc0\n\t"
    "global_load_dwordx4 %1, %13, off sc0\n\t"
    "global_load_dwordx4 %2, %14, off sc0\n\t"
    "global_load_dwordx4 %3, %15, off sc0\n\t"
    "global_load_ushort %4, %16, off sc0\n\t"
    "global_load_ushort %5, %17, off sc0\n\t"
    "global_load_ushort %6, %18, off sc0\n\t"
    "global_load_ushort %7, %19, off sc0\n\t"
    "global_load_ushort %8, %20, off sc0\n\t"
    "global_load_ushort %9, %21, off sc0\n\t"
    "global_load_ushort %10, %22, off sc0\n\t"
    "global_load_ushort %11, %23, off sc0\n\t"
    "s_waitcnt vmcnt(0)"
    : "=&v"(v0),"=&v"(v1),"=&v"(v2),"=&v"(v3),
      "=&v"(a0),"=&v"(a1),"=&v"(a2),"=&v"(a3),"=&v"(b0),"=&v"(b1),"=&v"(b2),"=&v"(b3)
    : "v"(p0), "v"(p0+512), "v"(p0+1024), "v"(p0+1536),
      "v"(pA),"v"(pA+8),"v"(pA+16),"v"(pA+24),
      "v"(pB),"v"(pB+8),"v"(pB+16),"v"(pB+24) : "memory");
  *(u32x4*)(dst + lane*8) = v0;
  *(u32x4*)(dst + lane*8 + 512) = v1;
  *(u32x4*)(dst + lane*8 + 1024) = v2;
  *(u32x4*)(dst + lane*8 + 1536) = v3;
  pvA[0]=bf2f((unsigned short)a0); pvA[1]=bf2f((unsigned short)a1);
  pvA[2]=bf2f((unsigned short)a2); pvA[3]=bf2f((unsigned short)a3);
  pvB[0]=bf2f((unsigned short)b0); pvB[1]=bf2f((unsigned short)b1);
  pvB[2]=bf2f((unsigned short)b2); pvB[3]=bf2f((unsigned short)b3);
}
// Linear 16KB tile copy global->LDS (fallback modes, 256 threads x 4 chunks).
template<bool FAST>
__device__ __forceinline__ void stage_lin4(const unsigned short* base, unsigned short* hl, int tid){
  const unsigned short* p0 = base + (size_t)tid * 8;
  u32x4 v0, v1, v2, v3;
  if constexpr (FAST)
    asm volatile("global_load_dwordx4 %0, %4, off sc0\n\t"
                 "global_load_dwordx4 %1, %5, off sc0\n\t"
                 "global_load_dwordx4 %2, %6, off sc0\n\t"
                 "global_load_dwordx4 %3, %7, off sc0\n\t"
                 "s_waitcnt vmcnt(0)"
                 : "=&v"(v0), "=&v"(v1), "=&v"(v2), "=&v"(v3)
                 : "v"(p0), "v"(p0+2048), "v"(p0+4096), "v"(p0+6144) : "memory");
  else
    asm volatile("global_load_dwordx4 %0, %4, off sc0 sc1\n\t"
                 "global_load_dwordx4 %1, %5, off sc0 sc1\n\t"
                 "global_load_dwordx4 %2, %6, off sc0 sc1\n\t"
                 "global_load_dwordx4 %3, %7, off sc0 sc1\n\t"
                 "s_waitcnt vmcnt(0)"
                 : "=&v"(v0), "=&v"(v1), "=&v"(v2), "=&v"(v3)
                 : "v"(p0), "v"(p0+2048), "v"(p0+4096), "v"(p0+6144) : "memory");
  *(u32x4*)(hl + tid*8) = v0;
  *(u32x4*)(hl + tid*8 + 2048) = v1;
  *(u32x4*)(hl + tid*8 + 4096) = v2;
  *(u32x4*)(hl + tid*8 + 6144) = v3;
}
// 4 bf16 scalar loads, chunk-order row walk (stride 8 shorts)
template<bool FAST>
__device__ __forceinline__ void ld4_chunk(const unsigned short* p, float* pv){
  unsigned u0,u1,u2,u3;
  if constexpr (FAST)
    asm volatile("global_load_ushort %0, %4, off sc0\n\t"
                 "global_load_ushort %1, %5, off sc0\n\t"
                 "global_load_ushort %2, %6, off sc0\n\t"
                 "global_load_ushort %3, %7, off sc0\n\t"
                 "s_waitcnt vmcnt(0)"
                 : "=&v"(u0), "=&v"(u1), "=&v"(u2), "=&v"(u3)
                 : "v"(p), "v"(p + 8), "v"(p + 16), "v"(p + 24) : "memory");
  else
    asm volatile("global_load_ushort %0, %4, off sc0 sc1\n\t"
                 "global_load_ushort %1, %5, off sc0 sc1\n\t"
                 "global_load_ushort %2, %6, off sc0 sc1\n\t"
                 "global_load_ushort %3, %7, off sc0 sc1\n\t"
                 "s_waitcnt vmcnt(0)"
                 : "=&v"(u0), "=&v"(u1), "=&v"(u2), "=&v"(u3)
                 : "v"(p), "v"(p + 8), "v"(p + 16), "v"(p + 24) : "memory");
  pv[0] = bf2f((unsigned short)u0); pv[1] = bf2f((unsigned short)u1);
  pv[2] = bf2f((unsigned short)u2); pv[3] = bf2f((unsigned short)u3);
}

// Dual-tile MFMA sweep over K=1024: each A-fragment read feeds BOTH tiles (A-reuse).
__device__ __forceinline__ void mfma_tile2(const char* lbase, const short8* wfA, const short8* wfB,
                                           int lrow, int kh, f32x4& outA, f32x4& outB){
  f32x4 z = {0.f,0.f,0.f,0.f};
  f32x4 a0 = z, a1 = z, b0 = z, b1 = z;
  int rb = kh * 128 + lrow * 16;
#pragma unroll
  for (int kk = 0; kk < 32; kk += 2){
    short8 x = *(const short8*)(lbase + kk*512 + rb);
    short8 y = *(const short8*)(lbase + (kk+1)*512 + rb);
    a0 = __builtin_amdgcn_mfma_f32_16x16x32_bf16(x, wfA[kk],   a0, 0,0,0);
    b0 = __builtin_amdgcn_mfma_f32_16x16x32_bf16(x, wfB[kk],   b0, 0,0,0);
    a1 = __builtin_amdgcn_mfma_f32_16x16x32_bf16(y, wfA[kk+1], a1, 0,0,0);
    b1 = __builtin_amdgcn_mfma_f32_16x16x32_bf16(y, wfB[kk+1], b1, 0,0,0);
  }
  outA = a0 + a1; outB = b0 + b1;
}

// ---------------- elementwise f32 -> bf16 ----------------
__global__ void cvt_bf16x8(const float* __restrict__ in, unsigned short* __restrict__ out,
                           long long n8){
  long long i = (long long)blockIdx.x * blockDim.x + threadIdx.x;
  long long stride = (long long)gridDim.x * blockDim.x;
  for (; i < n8; i += stride){
    const float* p = in + i*8;
    float4 a = *(const float4*)p;
    float4 b = *(const float4*)(p+4);
    short8 v;
    v[0]=(short)f2bf(a.x); v[1]=(short)f2bf(a.y); v[2]=(short)f2bf(a.z); v[3]=(short)f2bf(a.w);
    v[4]=(short)f2bf(b.x); v[5]=(short)f2bf(b.y); v[6]=(short)f2bf(b.z); v[7]=(short)f2bf(b.w);
    *(short8*)(out + i*8) = v;
  }
}

__global__ void bias_combine(const float* __restrict__ a, const float* __restrict__ b, float* __restrict__ o,
                             const float* __restrict__ c, const float* __restrict__ d, float* __restrict__ p){
  int i = blockIdx.x * blockDim.x + threadIdx.x;
  if (i < Hn){ o[i] = a[i] + b[i]; p[i] = c[i] + d[i]; }
}

// ---------------- pre0 GEMM: C[t*Bn+b][n] = sum_k x[b*Tn+t][k]*Wih0[n][k] + bias[n] ----------
__launch_bounds__(256, 2)
__global__ void gemm_pre0(const float* __restrict__ Av, const unsigned short* __restrict__ Bm,
                          const float* __restrict__ bias, unsigned short* __restrict__ C,
                          int N, int K)
{
  __shared__ unsigned short lA[128*64];
  __shared__ unsigned short lB[128*64];
  int bn = blockIdx.x, bm = blockIdx.y;
  int m0 = bm*128, n0 = bn*128;
  int tid = threadIdx.x, lane = tid & 63, w = tid >> 6;
  int wm = (w >> 1)*64, wn = (w & 1)*64;
  int cl = lane & 15, kh = lane >> 4;

  f32x4 acc[4][4];
  f32x4 z = {0.f,0.f,0.f,0.f};
#pragma unroll
  for (int i=0;i<4;i++)
#pragma unroll
    for (int j=0;j<4;j++) acc[i][j]=z;

  for (int k0 = 0; k0 < K; k0 += 64){
    __syncthreads();
#pragma unroll
    for (int r = 0; r < 4; ++r){
      int c = r*256 + tid;
      int row = c >> 3, cof = (c & 7)*8;
      const float* ap = Av + (size_t)(m0+row)*K + k0 + cof;
      float4 a = *(const float4*)ap;
      float4 b = *(const float4*)(ap+4);
      short8 v;
      v[0]=(short)f2bf(a.x); v[1]=(short)f2bf(a.y); v[2]=(short)f2bf(a.z); v[3]=(short)f2bf(a.w);
      v[4]=(short)f2bf(b.x); v[5]=(short)f2bf(b.y); v[6]=(short)f2bf(b.z); v[7]=(short)f2bf(b.w);
      *(short8*)&lA[row*64 + cof] = v;
      const unsigned short* bp = Bm + (size_t)(n0+row)*K + k0 + cof;
      *(short8*)&lB[row*64 + cof] = *(const short8*)bp;
    }
    __syncthreads();
#pragma unroll
    for (int kk = 0; kk < 2; ++kk){
      int kb = kk*32 + kh*8;
      short8 af[4], bfr[4];
#pragma unroll
      for (int i=0;i<4;i++) af[i]  = *(const short8*)&lA[(wm + i*16 + cl)*64 + kb];
#pragma unroll
      for (int j=0;j<4;j++) bfr[j] = *(const short8*)&lB[(wn + j*16 + cl)*64 + kb];
#pragma unroll
      for (int i=0;i<4;i++)
#pragma unroll
        for (int j=0;j<4;j++)
          acc[i][j] = __builtin_amdgcn_mfma_f32_16x16x32_bf16(af[i], bfr[j], acc[i][j], 0,0,0);
    }
  }
#pragma unroll
  for (int j=0;j<4;j++){
    int n = n0 + wn + j*16 + cl;
    float bs = bias[n];
#pragma unroll
    for (int i=0;i<4;i++){
      int mr = m0 + wm + i*16 + kh*4;
#pragma unroll
      for (int e=0;e<4;e++){
        int m = mr + e;                       // m = b*Tn + t
        int b = m >> 9, t = m & (Tn-1);
        C[((size_t)t*Bn + b)*N + n] = f2bf(acc[i][j][e] + bs);
      }
    }
  }
}

// ---------------- fused 3-stage recurrence (4 waves/wg, dual-tile A-reuse) ----------------
// 192 wgs, g = bx&7 (one XCD, runtime-verified); sub = bx>>3: role = sub>>3
// (0:L0-rec, 1:pre1-GEMV, 2:L1-rec), slot = sub&7 -> cols [128*slot,+128).
// 4 waves/wg: wave w owns tiles {2w,2w+1} (cols 32w..32w+32) over FULL K. Each
// A-fragment LDS read feeds 2 MFMAs -> 128 ds_read_b128/wg-step (was 256).
// Chunk-ordered 16KB tiles; slice s = 2KB at tile+s*1024. Aliasing (read-once-after-flag):
// h1(t)->tile t+2; pre1(t)->tile t; h2(t)->pre0 slice t.
// MODE0 flags: word [slot*4+w]; consumer wave w polls line FN+w*8 (covers wgs 2w,2w+1).
template<int MODE>
__device__ __forceinline__ void rnn_body(
    int role, int g, int slot, int tid, int w, int lane, int cl, int kh, int lrow,
    const unsigned short* pre0, unsigned short* bufP, unsigned short* h1buf,
    const float* bias1,
    unsigned int* FCA0, unsigned int* FCA1, unsigned int* FCB, unsigned int* FCC,
    unsigned int* FLA, unsigned int* FLB, unsigned int* FLC,
    unsigned int* FNA, unsigned int* FNB, unsigned int* FNC,
    const short8* wfA, const short8* wfB, unsigned short* hl, unsigned short* outl)
{
  constexpr bool FAST = (MODE < 2);
  int c0 = slot*128 + 32*w;                 // tile-pair base col
  int olocal = w*256 + ((cl>>3)*8 + kh*4)*8 + (cl&7);    // tile A; tile B at +128
  int khc = kh & 1;
  unsigned int* myFL = ((role == 0) ? FLA : (role == 1) ? FLB : FLC) + slot;
  unsigned int* myFN = ((role == 0) ? FNA : (role == 1) ? FNB : FNC) + slot*4 + w;

  float bsA = 0.f, bsB = 0.f;
  if (role == 1){ bsA = bias1[c0 + cl]; bsB = bias1[c0 + 16 + cl]; }

  for (int t = 0; t < Tn; ++t){
    unsigned short* hlb = (MODE == 0) ? hl + (t & 1)*8192 : hl;
    const char* lbase = (const char*)hlb;

    float pvA[4] = {0.f,0.f,0.f,0.f}, pvB[4] = {0.f,0.f,0.f,0.f};
    if (role == 0 && kh < 2){            // prefetch pre0 (plain cached; slice immutable here)
      const unsigned short* pp = pre0 + ((size_t)t*Bn + g*8 + kh*4)*Hn + c0 + cl;
#pragma unroll
      for (int j=0;j<4;j++){ pvA[j] = bf2f(pp[(size_t)j*Hn]); pvB[j] = bf2f(pp[(size_t)j*Hn + 16]); }
    }
    bool staged = true;
    if constexpr (MODE == 0){
      // ---- per-wave detect + 4KB (2-slice) stage ----
      if (role == 0){
        if (t > 0){
          wait8_nt(FNA + w*8, (unsigned)t);
          stage_pw4k(h1buf + ((size_t)(t+1)*8 + g)*8192 + 2*w*1024, hlb + 2*w*1024, lane);
        } else staged = false;
      } else if (role == 1){
        wait8_nt(FNA + w*8, (unsigned)(t+1));
        stage_pw4k(h1buf + ((size_t)(t+2)*8 + g)*8192 + 2*w*1024, hlb + 2*w*1024, lane);
      } else {
        const unsigned short* pb = h1buf + ((size_t)t*8 + g)*8192 + slot*1024;
        const unsigned short* pA = pb + ((c0 - slot*128 + cl) >> 3)*64 + khc*32 + (cl & 7);
        const unsigned short* pB = pA + 128;                        // +16 cols = +2 chunk groups
        if (t > 0){
          waitC_nt(FNC + w*8, (unsigned)t, FNB + slot*4 + w, (unsigned)(t+1));
          stage_pw4k_pv(bufP + ((size_t)(t-1)*Bn + g*8)*Hn + 2*w*1024, hlb + 2*w*1024, lane,
                        pA, pB, pvA, pvB);
        } else {
          staged = false;
          waitw_nt(FNB + slot*4 + w, 1u);
          ld4_chunk<true>(pA, pvA); ld4_chunk<true>(pB, pvB);
        }
      }
    } else {
      // ---- fallback modes: centralized tid0 wait + B1 + full stage (r12/r9/r4-proven) ----
      if (tid == 0){
        if (role == 0)      wait_one <FAST>(FCA0, FLA, 8u*(unsigned)t, (unsigned)t);
        else if (role == 1) wait_one <FAST>(FCA1, FLA, 8u*(unsigned)(t+1), (unsigned)(t+1));
        else                wait_dual<FAST>(FCB, FLB, 8u*(unsigned)(t+1), (unsigned)(t+1),
                                            FCC, FLC, 8u*(unsigned)t, (unsigned)t);
      }
      __syncthreads();                                             // B1
      if (role == 0){
        if (t > 0) stage_lin4<FAST>(h1buf + ((size_t)(t+1)*8 + g)*8192, hlb, tid);
        else staged = false;
      } else if (role == 1){
        stage_lin4<FAST>(h1buf + ((size_t)(t+2)*8 + g)*8192, hlb, tid);
      } else {
        const unsigned short* pb = h1buf + ((size_t)t*8 + g)*8192 + slot*1024;
        const unsigned short* pA = pb + ((32*w + cl) >> 3)*64 + kh*32 + (cl & 7);
        if (kh < 2){ ld4_chunk<FAST>(pA, pvA); ld4_chunk<FAST>(pA + 128, pvB); }
        if (t > 0) stage_lin4<FAST>(bufP + ((size_t)(t-1)*Bn + g*8)*Hn, hlb, tid);
        else staged = false;
      }
    }
    __syncthreads();                                               // B2 (tile staged)
    // ---- compute: dual-tile, full K, A-reuse ----
    f32x4 accA = {0.f,0.f,0.f,0.f}, accB = accA;
    if (staged) mfma_tile2(lbase, wfA, wfB, lrow, kh, accA, accB);
    // ---- transpose to wave-private LDS, vector-store 2 slices ----
    if (kh < 2){
#pragma unroll
      for (int j=0;j<4;j++){
        float vA = accA[j] + pvA[j] + bsA;
        float vB = accB[j] + pvB[j] + bsB;
        if (role != 1){ vA = tanh_fast(vA); vB = tanh_fast(vB); }
        outl[olocal + j*8]       = f2bf(vA);
        outl[olocal + 128 + j*8] = f2bf(vB);
      }
    }
    unsigned short* tile;
    if (role == 0)      tile = h1buf + ((size_t)(t+2)*8 + g)*8192;
    else if (role == 1) tile = h1buf + ((size_t)t*8 + g)*8192;
    else                tile = bufP + ((size_t)t*Bn + g*8)*Hn;
    tile += slot*1024;
    if (lane < 16){
      st16<FAST>(tile + (32*w + lane)*8,      *(const u32x4*)(outl + w*256 + lane*8));
      st16<FAST>(tile + (32*w + 16 + lane)*8, *(const u32x4*)(outl + w*256 + 128 + lane*8));
    }
    if constexpr (MODE == 0){
      // per-wave publish: drain own stores, lane0 sets this wave's flag word. No barrier.
      asm volatile("s_waitcnt vmcnt(0)" ::: "memory");
      if (lane == 0)
        asm volatile("global_store_dword %0, %1, off sc0" :: "v"(myFN), "v"((unsigned)(t+1)) : "memory");
    } else {
      asm volatile("s_waitcnt vmcnt(0)" ::: "memory");
      __syncthreads();                                             // B3
      if (tid == 0){
        if constexpr (MODE == 1){
          if (role == 0){ atom_inc(FCA0); atom_inc(FCA1); }
          else if (role == 1) atom_inc(FCB);
          else atom_inc(FCC);
        } else {
          asm volatile("global_store_dword %0, %1, off sc0 sc1" :: "v"(myFL), "v"((unsigned)(t+1)) : "memory");
        }
      }
    }
  }
}

__launch_bounds__(256, 1)
__global__ void rnn_fused(const unsigned short* __restrict__ pre0_ro,
                          unsigned short* __restrict__ bufP,
                          unsigned short* __restrict__ h1buf,
                          const float* __restrict__ Whh0,
                          const float* __restrict__ Wih1,
                          const float* __restrict__ Whh1,
                          const float* __restrict__ bias1,
                          unsigned int* ctrs)
{
  __shared__ __align__(16) unsigned short hl[16384];   // 2 x 16KB staged tile (chunk order)
  __shared__ __align__(16) unsigned short outl[1024];  // 4 waves x 2 tiles x 128 shorts
  __shared__ int s_mode;
  int bx = blockIdx.x;
  int g = bx & 7;
  int sub = bx >> 3;
  int role = sub >> 3, slot = sub & 7;
  int tid = threadIdx.x, lane = tid & 63, w = tid >> 6;      // w in [0,4)
  int cl = lane & 15, kh = lane >> 4, lrow = cl & 7;
  unsigned int* FLA = ctrs + (0*8 + g)*32;   // MALL flag lines (8 words each)
  unsigned int* FLB = ctrs + (1*8 + g)*32;
  unsigned int* FLC = ctrs + (2*8 + g)*32;
  unsigned int* arrive1 = ctrs + 768;
  unsigned int* badAT   = ctrs + 772;
  unsigned int* arrive2 = ctrs + 776;
  unsigned int* badNT   = ctrs + 780;
  unsigned int* arrive3 = ctrs + 784;
  unsigned int* FCA0 = ctrs + 1536 + (0*8 + g)*32;  // MODE1 counters (128B-spaced)
  unsigned int* FCB  = ctrs + 1536 + (1*8 + g)*32;
  unsigned int* FCC  = ctrs + 1536 + (2*8 + g)*32;
  unsigned int* FCA1 = ctrs + 1536 + (3*8 + g)*32;
  unsigned int* FNA = ctrs + 2560 + (0*8 + g)*32;   // MODE0 per-(slot,wave) flags, 32 words
  unsigned int* FNB = ctrs + 2560 + (1*8 + g)*32;
  unsigned int* FNC = ctrs + 2560 + (2*8 + g)*32;

  // ---- one-time self-tests: NT sequence, then ATOM sequence; consensus via bad flags ----
  if (tid == 0){
    int xcc;
    asm volatile("s_getreg_b32 %0, hwreg(HW_REG_XCC_ID)" : "=s"(xcc));
    unsigned int* atw = ctrs + 1024 + g*32;  unsigned int* atarmed = atw + 16;
    unsigned int* ntw = ctrs + 1280 + g*32;  unsigned int* ntarmed = ntw + 16;
    if (xcc != g){
      __hip_atomic_fetch_or(badNT, 1u, __ATOMIC_RELAXED, __HIP_MEMORY_SCOPE_AGENT);
      __hip_atomic_fetch_or(badAT, 1u, __ATOMIC_RELAXED, __HIP_MEMORY_SCOPE_AGENT);
    }
    unsigned pr = ld1_nt(ntw) + ld1_nt(ntarmed);   // prime NT lines (stale-L1 hazard probe)
    asm volatile("" :: "v"(pr));
    __hip_atomic_fetch_add(arrive1, 1u, __ATOMIC_ACQ_REL, __HIP_MEMORY_SCOPE_AGENT);
    int t1 = 0;
    for (int i = 0; i < (1 << 20); ++i){
      if (__hip_atomic_load(arrive1, __ATOMIC_ACQUIRE, __HIP_MEMORY_SCOPE_AGENT) >= 192u){ t1 = 1; break; }
      __builtin_amdgcn_s_sleep(2);
    }
    if (!t1){
      __hip_atomic_fetch_or(badNT, 1u, __ATOMIC_RELAXED, __HIP_MEMORY_SCOPE_AGENT);
      __hip_atomic_fetch_or(badAT, 1u, __ATOMIC_RELAXED, __HIP_MEMORY_SCOPE_AGENT);
    }
    unsigned magicN = 0xBEEF0000u | (unsigned)g;
    if (sub == 0){
      asm volatile("global_store_dword %0, %1, off sc0\n\t"
                   "s_waitcnt vmcnt(0)\n\t"
                   "global_store_dword %2, %3, off sc0"
                   :: "v"(ntw), "v"(magicN), "v"(ntarmed), "v"(1u) : "memory");
    }
    int okN = 0;
    for (int i = 0; i < (1 << 14); ++i){
      if (ld1_nt(ntarmed) == 1u){ okN = (ld1_nt(ntw) == magicN); break; }
      if (i > 8) __builtin_amdgcn_s_sleep(1);
    }
    if (!okN) __hip_atomic_fetch_or(badNT, 1u, __ATOMIC_RELAXED, __HIP_MEMORY_SCOPE_AGENT);
    __hip_atomic_fetch_add(arrive2, 1u, __ATOMIC_ACQ_REL, __HIP_MEMORY_SCOPE_AGENT);
    int t2 = 0;
    for (int i = 0; i < (1 << 20); ++i){
      if (__hip_atomic_load(arrive2, __ATOMIC_ACQUIRE, __HIP_MEMORY_SCOPE_AGENT) >= 192u){ t2 = 1; break; }
      __builtin_amdgcn_s_sleep(2);
    }
    if (!t2){
      __hip_atomic_fetch_or(badNT, 1u, __ATOMIC_RELAXED, __HIP_MEMORY_SCOPE_AGENT);
      __hip_atomic_fetch_or(badAT, 1u, __ATOMIC_RELAXED, __HIP_MEMORY_SCOPE_AGENT);
    }
    unsigned magicA = 0xCAFE0000u | (unsigned)g;
    if (sub == 0){
      asm volatile("global_store_dword %0, %1, off sc0\n\t"
                   "s_waitcnt vmcnt(0)" :: "v"(atw), "v"(magicA) : "memory");
      atom_inc(atarmed);
    }
    int okA = 0;
    for (int i = 0; i < (1 << 15); ++i){
      if (atom_poll(atarmed) >= 1u){ okA = (ld1_sc0(atw) == magicA); break; }
      if (i > 16) __builtin_amdgcn_s_sleep(1);
    }
    if (!okA) __hip_atomic_fetch_or(badAT, 1u, __ATOMIC_RELAXED, __HIP_MEMORY_SCOPE_AGENT);
    __hip_atomic_fetch_add(arrive3, 1u, __ATOMIC_ACQ_REL, __HIP_MEMORY_SCOPE_AGENT);
    int t3 = 0;
    for (int i = 0; i < (1 << 20); ++i){
      if (__hip_atomic_load(arrive3, __ATOMIC_ACQUIRE, __HIP_MEMORY_SCOPE_AGENT) >= 192u){ t3 = 1; break; }
      __builtin_amdgcn_s_sleep(2);
    }
    unsigned bN = __hip_atomic_load(badNT, __ATOMIC_ACQUIRE, __HIP_MEMORY_SCOPE_AGENT);
    unsigned bA = __hip_atomic_load(badAT, __ATOMIC_ACQUIRE, __HIP_MEMORY_SCOPE_AGENT);
    s_mode = (!t3) ? 2 : (bN == 0u ? 0 : (bA == 0u ? 1 : 2));
  }
  __syncthreads();
  const int mode = s_mode;

  // Resident weight fragments for tile pair: wfA = cols c0..c0+16, wfB = +16.
  // lane (cl,kh), frag kk: W[col][kk*32 + kh*8 .. +8]
  const float* Wmat = (role == 0) ? Whh0 : (role == 1) ? Wih1 : Whh1;
  int c0 = slot*128 + 32*w;
  short8 wfA[32], wfB[32];
  {
    const float* wrA = Wmat + (size_t)(c0 + cl)*Hn + kh*8;
    const float* wrB = wrA + (size_t)16*Hn;
#pragma unroll
    for (int kk = 0; kk < 32; ++kk){
      {
        float4 a = *(const float4*)(wrA + kk*32);
        float4 b = *(const float4*)(wrA + kk*32 + 4);
        short8 v;
        v[0]=(short)f2bf(a.x); v[1]=(short)f2bf(a.y); v[2]=(short)f2bf(a.z); v[3]=(short)f2bf(a.w);
        v[4]=(short)f2bf(b.x); v[5]=(short)f2bf(b.y); v[6]=(short)f2bf(b.z); v[7]=(short)f2bf(b.w);
        wfA[kk] = v;
      }
      {
        float4 a = *(const float4*)(wrB + kk*32);
        float4 b = *(const float4*)(wrB + kk*32 + 4);
        short8 v;
        v[0]=(short)f2bf(a.x); v[1]=(short)f2bf(a.y); v[2]=(short)f2bf(a.z); v[3]=(short)f2bf(a.w);
        v[4]=(short)f2bf(b.x); v[5]=(short)f2bf(b.y); v[6]=(short)f2bf(b.z); v[7]=(short)f2bf(b.w);
        wfB[kk] = v;
      }
    }
  }

  if (mode == 0)
    rnn_body<0>(role, g, slot, tid, w, lane, cl, kh, lrow, pre0_ro, bufP, h1buf,
                bias1, FCA0, FCA1, FCB, FCC, FLA, FLB, FLC, FNA, FNB, FNC, wfA, wfB, hl, outl);
  else if (mode == 1)
    rnn_body<1>(role, g, slot, tid, w, lane, cl, kh, lrow, pre0_ro, bufP, h1buf,
                bias1, FCA0, FCA1, FCB, FCC, FLA, FLB, FLC, FNA, FNB, FNC, wfA, wfB, hl, outl);
  else
    rnn_body<2>(role, g, slot, tid, w, lane, cl, kh, lrow, pre0_ro, bufP, h1buf,
                bias1, FCA0, FCA1, FCB, FCC, FLA, FLB, FLC, FNA, FNB, FNC, wfA, wfB, hl, outl);
}

// ---------------- FC head: out[b][o] = h2[b][T-1][:] . Wfc[o][:] + bfc[o] ----------------
__global__ void fc_k(const unsigned short* __restrict__ bufP,
                     const float* __restrict__ Wfc, const float* __restrict__ bfc,
                     float* __restrict__ out)
{
  int gw = (blockIdx.x * blockDim.x + threadIdx.x) >> 6;
  int lane = threadIdx.x & 63;
  int b = gw >> 7, o = gw & 127;
  // h2(T-1) lives in pre0 slice T-1, group tile (b>>3), chunk-ordered
  const unsigned short* tile = bufP + ((size_t)(Tn-1)*Bn + (b & ~7))*Hn;
  int r = b & 7;
  const float* wr = Wfc + (size_t)o*Hn;
  float s = 0.f;
  for (int k = lane; k < Hn; k += 64)
    s += bf2f(tile[((k>>3)*8 + r)*8 + (k&7)]) * wr[k];
#pragma unroll
  for (int off = 32; off > 0; off >>= 1) s += __shfl_down(s, off, 64);
  if (lane == 0) out[b*OUTn + o] = s + bfc[o];
}

// ---------------- host ----------------
extern "C" void kernel_launch(void* const* d_in, const int* in_sizes, int n_in,
                              void* d_out, int out_size, void* d_ws, size_t ws_size,
                              hipStream_t stream)
{
  const float* x    = (const float*)d_in[0];
  const float* Wih0 = (const float*)d_in[1];
  const float* Whh0 = (const float*)d_in[2];
  const float* bih0 = (const float*)d_in[3];
  const float* bhh0 = (const float*)d_in[4];
  const float* Wih1 = (const float*)d_in[5];
  const float* Whh1 = (const float*)d_in[6];
  const float* bih1 = (const float*)d_in[7];
  const float* bhh1 = (const float*)d_in[8];
  const float* Wfc  = (const float*)d_in[9];
  const float* bfc  = (const float*)d_in[10];
  float* out = (float*)d_out;

  // workspace (bf16 elements)
  unsigned short* bufP  = (unsigned short*)d_ws;                    // pre0 [T][B][H]; h2 aliases slices
  unsigned short* h1buf = bufP  + (size_t)Bn*Tn*Hn;                 // (T+2)*8 chunk-ordered 16KB tiles
  unsigned short* wih0b = h1buf + (size_t)(Tn+2)*8*8192;            // 1MiB
  float* bias0 = (float*)(wih0b + (size_t)Hn*DINn);
  float* bias1 = bias0 + Hn;
  unsigned int* ctrs = (unsigned int*)(bias1 + Hn);                 // 4096 uints

  hipMemsetAsync(ctrs, 0, 4096*sizeof(unsigned int), stream);

  cvt_bf16x8<<<256, 256, 0, stream>>>(Wih0, wih0b, (long long)Hn*DINn/8);
  bias_combine<<<4, 256, 0, stream>>>(bih0, bhh0, bias0, bih1, bhh1, bias1);

  // pre0 = x @ Wih0^T + bias0, written as [T][B][H]
  dim3 g1(Hn/128, (Bn*Tn)/128);
  gemm_pre0<<<g1, 256, 0, stream>>>(x, wih0b, bias0, bufP, Hn, DINn);

  // fused 3-stage pipeline (4 waves/wg, dual-tile A-reuse; NT/ATOM/MALL flags)
  rnn_fused<<<192, 256, 0, stream>>>(bufP, bufP, h1buf, Whh0, Wih1, Whh1, bias1, ctrs);

  // FC head from h2(T-1) (aliased into pre0 slice T-1)
  fc_k<<<2048, 256, 0, stream>>>(bufP, Wfc, bfc, out);
}

// Round 21
// 1126.963 us; speedup vs baseline: 1.2624x; 1.2624x over previous
//
#include <hip/hip_runtime.h>
#include <stdint.h>
#include <stddef.h>

// Problem dims
#define Bn   64
#define Tn   512
#define DINn 512
#define Hn   1024
#define OUTn 128

typedef __attribute__((ext_vector_type(4))) float f32x4;
typedef __attribute__((ext_vector_type(8))) short short8;
typedef __attribute__((ext_vector_type(4))) unsigned int u32x4;

__device__ __forceinline__ unsigned short f2bf(float f){
  unsigned int x = __builtin_bit_cast(unsigned int, f);
  x += 0x7fffu + ((x >> 16) & 1u);           // RNE (values bounded, no NaN/inf)
  return (unsigned short)(x >> 16);
}
__device__ __forceinline__ float bf2f(unsigned short u){
  return __builtin_bit_cast(float, (unsigned int)u << 16);
}
__device__ __forceinline__ float tanh_fast(float v){
  float e = __expf(2.0f * v);
  return 1.0f - 2.0f / (e + 1.0f);
}

// ---- protocol primitives ----
// MODE 0 (NT, r14-proven + r19 per-wave publish): XCD-local flags. Producer WAVE w of wg
//   (role,slot) publishes flag word [slot*8+w] after draining ITS OWN sc0 stores — no
//   post-store barrier, no tid0 funnel. Consumers min-poll the producer wg's 8-word line
//   (nt loads bypass L1). hl double-buffered (t&1) so the single B2 barrier suffices.
// MODE 1 (ATOM): r9-proven. Flags via MALL atomics. MODE 2 (MALL): r4-proven, sc0 sc1.
template<bool FAST>
__device__ __forceinline__ void st16(unsigned short* p, u32x4 v){
  if constexpr (FAST)
    asm volatile("global_store_dwordx4 %0, %1, off sc0" :: "v"(p), "v"(v) : "memory");
  else
    asm volatile("global_store_dwordx4 %0, %1, off sc0 sc1" :: "v"(p), "v"(v) : "memory");
}
__device__ __forceinline__ unsigned atom_poll(unsigned int* p){
  unsigned old, zero = 0;
  asm volatile("global_atomic_add %0, %1, %2, off sc0\n\t"
               "s_waitcnt vmcnt(0)"
               : "=&v"(old) : "v"(p), "v"(zero) : "memory");
  return old;
}
__device__ __forceinline__ void atom_poll2(unsigned int* p1, unsigned int* p2,
                                           unsigned &v1, unsigned &v2){
  unsigned zero = 0;
  asm volatile("global_atomic_add %0, %2, %4, off sc0\n\t"
               "global_atomic_add %1, %3, %4, off sc0\n\t"
               "s_waitcnt vmcnt(0)"
               : "=&v"(v1), "=&v"(v2)
               : "v"(p1), "v"(p2), "v"(zero) : "memory");
}
__device__ __forceinline__ void atom_inc(unsigned int* p){
  unsigned one = 1;
  asm volatile("global_atomic_add %0, %1, off" :: "v"(p), "v"(one) : "memory");
}
__device__ __forceinline__ unsigned ld1_sc0(const unsigned int* p){
  unsigned v;
  asm volatile("global_load_dword %0, %1, off sc0\n\t"
               "s_waitcnt vmcnt(0)" : "=&v"(v) : "v"(p) : "memory");
  return v;
}
__device__ __forceinline__ unsigned ld1_nt(const unsigned int* p){
  unsigned v;
  asm volatile("global_load_dword %0, %1, off nt\n\t"
               "s_waitcnt vmcnt(0)" : "=&v"(v) : "v"(p) : "memory");
  return v;
}
__device__ __forceinline__ unsigned umin4(u32x4 a){
  unsigned m0 = a[0] < a[1] ? a[0] : a[1];
  unsigned m1 = a[2] < a[3] ? a[2] : a[3];
  return m0 < m1 ? m0 : m1;
}
__device__ __forceinline__ unsigned ld_line8_nt(const unsigned int* p){
  u32x4 a, b;
  asm volatile("global_load_dwordx4 %0, %2, off nt\n\t"
               "global_load_dwordx4 %1, %3, off nt\n\t"
               "s_waitcnt vmcnt(0)"
               : "=&v"(a), "=&v"(b) : "v"(p), "v"(p + 4) : "memory");
  unsigned ma = umin4(a), mb = umin4(b);
  return ma < mb ? ma : mb;
}
__device__ __forceinline__ unsigned ld_line8_slow(const unsigned int* p){
  u32x4 a, b;
  asm volatile("global_load_dwordx4 %0, %2, off sc0 sc1\n\t"
               "global_load_dwordx4 %1, %3, off sc0 sc1\n\t"
               "s_waitcnt vmcnt(0)"
               : "=&v"(a), "=&v"(b) : "v"(p), "v"(p + 4) : "memory");
  unsigned ma = umin4(a), mb = umin4(b);
  return ma < mb ? ma : mb;
}
// Bounded waits. Worst case returns late -> visibly wrong, never a hang.
__device__ __forceinline__ void wait8_nt(const unsigned int* p, unsigned want){
  if (!want) return;
  for (int i = 0; i < (1 << 16); ++i){
    if (ld_line8_nt(p) >= want) return;
    if (i > 16) __builtin_amdgcn_s_sleep(1);
  }
}
__device__ __forceinline__ void wait8_nt2(const unsigned int* p1, unsigned w1,
                                          const unsigned int* p2, unsigned w2){
  if (!w1){ wait8_nt(p2, w2); return; }
  for (int i = 0; i < (1 << 16); ++i){
    u32x4 a, b, c, d;
    asm volatile("global_load_dwordx4 %0, %4, off nt\n\t"
                 "global_load_dwordx4 %1, %5, off nt\n\t"
                 "global_load_dwordx4 %2, %6, off nt\n\t"
                 "global_load_dwordx4 %3, %7, off nt\n\t"
                 "s_waitcnt vmcnt(0)"
                 : "=&v"(a), "=&v"(b), "=&v"(c), "=&v"(d)
                 : "v"(p1), "v"(p1 + 4), "v"(p2), "v"(p2 + 4) : "memory");
    unsigned m1 = umin4(a) < umin4(b) ? umin4(a) : umin4(b);
    unsigned m2 = umin4(c) < umin4(d) ? umin4(c) : umin4(d);
    if (m1 >= w1 && m2 >= w2) return;
    if (i > 16) __builtin_amdgcn_s_sleep(1);
  }
}
template<bool FAST>
__device__ __forceinline__ void wait_one(unsigned int* fc, unsigned int* fl, unsigned wfast, unsigned wslow){
  if constexpr (FAST){
    if (!wfast) return;
    for (int i = 0; i < (1 << 16); ++i){
      if (atom_poll(fc) >= wfast) return;
      if (i > 8) __builtin_amdgcn_s_sleep(1);
    }
  } else {
    if (!wslow) return;
    for (int i = 0; i < (1 << 16); ++i){
      if (ld_line8_slow(fl) >= wslow) return;
      if (i > 16) __builtin_amdgcn_s_sleep(1);
    }
  }
}
template<bool FAST>
__device__ __forceinline__ void wait_dual(unsigned int* fc1, unsigned int* fl1, unsigned wf1, unsigned ws1,
                                          unsigned int* fc2, unsigned int* fl2, unsigned wf2, unsigned ws2){
  if constexpr (FAST){
    if (!wf2){ wait_one<true>(fc1, fl1, wf1, ws1); return; }
    for (int i = 0; i < (1 << 16); ++i){
      unsigned v1, v2;
      atom_poll2(fc1, fc2, v1, v2);
      if (v1 >= wf1 && v2 >= wf2) return;
      if (i > 8) __builtin_amdgcn_s_sleep(1);
    }
  } else {
    if (!ws2){ wait_one<false>(fc1, fl1, wf1, ws1); return; }
    for (int i = 0; i < (1 << 16); ++i){
      if (ld_line8_slow(fl1) >= ws1 && ld_line8_slow(fl2) >= ws2) return;
      if (i > 16) __builtin_amdgcn_s_sleep(1);
    }
  }
}

// Per-wave 2KB slice copy global->LDS (slice = 1024 shorts, lane-parallel, sc0).
__device__ __forceinline__ void stage_pw(const unsigned short* src, unsigned short* dst, int lane){
  const unsigned short* p0 = src + lane*8;
  const unsigned short* p1 = p0 + 512;
  u32x4 v0, v1;
  asm volatile("global_load_dwordx4 %0, %2, off sc0\n\t"
               "global_load_dwordx4 %1, %3, off sc0\n\t"
               "s_waitcnt vmcnt(0)"
               : "=&v"(v0), "=&v"(v1) : "v"(p0), "v"(p1) : "memory");
  *(u32x4*)(dst + lane*8) = v0;
  *(u32x4*)(dst + lane*8 + 512) = v1;
}
// Per-wave 2KB slice + 4 bf16 pv loads, one drain.
__device__ __forceinline__ void stage_pw_pv(const unsigned short* src, unsigned short* dst, int lane,
                                            const unsigned short* p4, float* pv){
  const unsigned short* p0 = src + lane*8;
  const unsigned short* p1 = p0 + 512;
  u32x4 v0, v1; unsigned u0,u1,u2,u3;
  asm volatile(
    "global_load_dwordx4 %0, %6, off sc0\n\t"
    "global_load_dwordx4 %1, %7, off sc0\n\t"
    "global_load_ushort %2, %8, off sc0\n\t"
    "global_load_ushort %3, %9, off sc0\n\t"
    "global_load_ushort %4, %10, off sc0\n\t"
    "global_load_ushort %5, %11, off sc0\n\t"
    "s_waitcnt vmcnt(0)"
    : "=&v"(v0),"=&v"(v1),"=&v"(u0),"=&v"(u1),"=&v"(u2),"=&v"(u3)
    : "v"(p0),"v"(p1),"v"(p4),"v"(p4+8),"v"(p4+16),"v"(p4+24) : "memory");
  *(u32x4*)(dst + lane*8) = v0;
  *(u32x4*)(dst + lane*8 + 512) = v1;
  pv[0]=bf2f((unsigned short)u0); pv[1]=bf2f((unsigned short)u1);
  pv[2]=bf2f((unsigned short)u2); pv[3]=bf2f((unsigned short)u3);
}

// Linear 16KB tile copy global->LDS (fallback modes).
template<bool FAST>
__device__ __forceinline__ void stage_lin(const unsigned short* base, unsigned short* hl, int tid){
  const unsigned short* p0 = base + (size_t)tid * 8;
  const unsigned short* p1 = p0 + 4096;
  u32x4 v0, v1;
  if constexpr (FAST)
    asm volatile("global_load_dwordx4 %0, %2, off sc0\n\t"
                 "global_load_dwordx4 %1, %3, off sc0\n\t"
                 "s_waitcnt vmcnt(0)"
                 : "=&v"(v0), "=&v"(v1) : "v"(p0), "v"(p1) : "memory");
  else
    asm volatile("global_load_dwordx4 %0, %2, off sc0 sc1\n\t"
                 "global_load_dwordx4 %1, %3, off sc0 sc1\n\t"
                 "s_waitcnt vmcnt(0)"
                 : "=&v"(v0), "=&v"(v1) : "v"(p0), "v"(p1) : "memory");
  *(u32x4*)((char*)hl + tid * 16) = v0;
  *(u32x4*)((char*)hl + tid * 16 + 8192) = v1;
}
// 4 bf16 scalar loads, chunk-order row walk (stride 8 shorts)
template<bool FAST>
__device__ __forceinline__ void ld4_chunk(const unsigned short* p, float* pv){
  unsigned u0,u1,u2,u3;
  if constexpr (FAST)
    asm volatile("global_load_ushort %0, %4, off sc0\n\t"
                 "global_load_ushort %1, %5, off sc0\n\t"
                 "global_load_ushort %2, %6, off sc0\n\t"
                 "global_load_ushort %3, %7, off sc0\n\t"
                 "s_waitcnt vmcnt(0)"
                 : "=&v"(u0), "=&v"(u1), "=&v"(u2), "=&v"(u3)
                 : "v"(p), "v"(p + 8), "v"(p + 16), "v"(p + 24) : "memory");
  else
    asm volatile("global_load_ushort %0, %4, off sc0 sc1\n\t"
                 "global_load_ushort %1, %5, off sc0 sc1\n\t"
                 "global_load_ushort %2, %6, off sc0 sc1\n\t"
                 "global_load_ushort %3, %7, off sc0 sc1\n\t"
                 "s_waitcnt vmcnt(0)"
                 : "=&v"(u0), "=&v"(u1), "=&v"(u2), "=&v"(u3)
                 : "v"(p), "v"(p + 8), "v"(p + 16), "v"(p + 24) : "memory");
  pv[0] = bf2f((unsigned short)u0); pv[1] = bf2f((unsigned short)u1);
  pv[2] = bf2f((unsigned short)u2); pv[3] = bf2f((unsigned short)u3);
}

// MFMA sweep over K=1024 on chunk-ordered LDS tile (conflict-free, r12-proven).
__device__ __forceinline__ f32x4 mfma_tile(const char* lbase, const short8* wf, int lrow, int kh){
  f32x4 a0 = {0.f,0.f,0.f,0.f}, a1 = a0, a2 = a0, a3 = a0;
  int rb = kh * 128 + lrow * 16;
#pragma unroll
  for (int kk = 0; kk < 8; ++kk)
    a0 = __builtin_amdgcn_mfma_f32_16x16x32_bf16(*(const short8*)(lbase + kk*512 + rb), wf[kk], a0, 0,0,0);
#pragma unroll
  for (int kk = 8; kk < 16; ++kk)
    a1 = __builtin_amdgcn_mfma_f32_16x16x32_bf16(*(const short8*)(lbase + kk*512 + rb), wf[kk], a1, 0,0,0);
#pragma unroll
  for (int kk = 16; kk < 24; ++kk)
    a2 = __builtin_amdgcn_mfma_f32_16x16x32_bf16(*(const short8*)(lbase + kk*512 + rb), wf[kk], a2, 0,0,0);
#pragma unroll
  for (int kk = 24; kk < 32; ++kk)
    a3 = __builtin_amdgcn_mfma_f32_16x16x32_bf16(*(const short8*)(lbase + kk*512 + rb), wf[kk], a3, 0,0,0);
  return (a0 + a1) + (a2 + a3);
}

// ---------------- elementwise f32 -> bf16 ----------------
__global__ void cvt_bf16x8(const float* __restrict__ in, unsigned short* __restrict__ out,
                           long long n8){
  long long i = (long long)blockIdx.x * blockDim.x + threadIdx.x;
  long long stride = (long long)gridDim.x * blockDim.x;
  for (; i < n8; i += stride){
    const float* p = in + i*8;
    float4 a = *(const float4*)p;
    float4 b = *(const float4*)(p+4);
    short8 v;
    v[0]=(short)f2bf(a.x); v[1]=(short)f2bf(a.y); v[2]=(short)f2bf(a.z); v[3]=(short)f2bf(a.w);
    v[4]=(short)f2bf(b.x); v[5]=(short)f2bf(b.y); v[6]=(short)f2bf(b.z); v[7]=(short)f2bf(b.w);
    *(short8*)(out + i*8) = v;
  }
}

__global__ void bias_combine(const float* __restrict__ a, const float* __restrict__ b, float* __restrict__ o,
                             const float* __restrict__ c, const float* __restrict__ d, float* __restrict__ p){
  int i = blockIdx.x * blockDim.x + threadIdx.x;
  if (i < Hn){ o[i] = a[i] + b[i]; p[i] = c[i] + d[i]; }
}

// ---------------- pre0 GEMM: C[t*Bn+b][n] = sum_k x[b*Tn+t][k]*Wih0[n][k] + bias[n] ----------
__launch_bounds__(256, 2)
__global__ void gemm_pre0(const float* __restrict__ Av, const unsigned short* __restrict__ Bm,
                          const float* __restrict__ bias, unsigned short* __restrict__ C,
                          int N, int K)
{
  __shared__ unsigned short lA[128*64];
  __shared__ unsigned short lB[128*64];
  int bn = blockIdx.x, bm = blockIdx.y;
  int m0 = bm*128, n0 = bn*128;
  int tid = threadIdx.x, lane = tid & 63, w = tid >> 6;
  int wm = (w >> 1)*64, wn = (w & 1)*64;
  int cl = lane & 15, kh = lane >> 4;

  f32x4 acc[4][4];
  f32x4 z = {0.f,0.f,0.f,0.f};
#pragma unroll
  for (int i=0;i<4;i++)
#pragma unroll
    for (int j=0;j<4;j++) acc[i][j]=z;

  for (int k0 = 0; k0 < K; k0 += 64){
    __syncthreads();
#pragma unroll
    for (int r = 0; r < 4; ++r){
      int c = r*256 + tid;
      int row = c >> 3, cof = (c & 7)*8;
      const float* ap = Av + (size_t)(m0+row)*K + k0 + cof;
      float4 a = *(const float4*)ap;
      float4 b = *(const float4*)(ap+4);
      short8 v;
      v[0]=(short)f2bf(a.x); v[1]=(short)f2bf(a.y); v[2]=(short)f2bf(a.z); v[3]=(short)f2bf(a.w);
      v[4]=(short)f2bf(b.x); v[5]=(short)f2bf(b.y); v[6]=(short)f2bf(b.z); v[7]=(short)f2bf(b.w);
      *(short8*)&lA[row*64 + cof] = v;
      const unsigned short* bp = Bm + (size_t)(n0+row)*K + k0 + cof;
      *(short8*)&lB[row*64 + cof] = *(const short8*)bp;
    }
    __syncthreads();
#pragma unroll
    for (int kk = 0; kk < 2; ++kk){
      int kb = kk*32 + kh*8;
      short8 af[4], bfr[4];
#pragma unroll
      for (int i=0;i<4;i++) af[i]  = *(const short8*)&lA[(wm + i*16 + cl)*64 + kb];
#pragma unroll
      for (int j=0;j<4;j++) bfr[j] = *(const short8*)&lB[(wn + j*16 + cl)*64 + kb];
#pragma unroll
      for (int i=0;i<4;i++)
#pragma unroll
        for (int j=0;j<4;j++)
          acc[i][j] = __builtin_amdgcn_mfma_f32_16x16x32_bf16(af[i], bfr[j], acc[i][j], 0,0,0);
    }
  }
#pragma unroll
  for (int j=0;j<4;j++){
    int n = n0 + wn + j*16 + cl;
    float bs = bias[n];
#pragma unroll
    for (int i=0;i<4;i++){
      int mr = m0 + wm + i*16 + kh*4;
#pragma unroll
      for (int e=0;e<4;e++){
        int m = mr + e;                       // m = b*Tn + t
        int b = m >> 9, t = m & (Tn-1);
        C[((size_t)t*Bn + b)*N + n] = f2bf(acc[i][j][e] + bs);
      }
    }
  }
}

// ---------------- fused 3-stage recurrence (MODE0: per-wave detect + per-wave publish) --------
// 192 wgs, g = bx&7 (one XCD, runtime-verified); sub = bx>>3: role = sub>>3
// (0:L0-rec, 1:pre1-GEMV, 2:L1-rec), slot = sub&7 -> cols [128*slot,+128).
// Chunk-ordered 16KB tiles; slot s's slice = contiguous 2KB at tile+s*1024 shorts.
// Aliasing (read-once-after-flag): h1(t)->tile t+2; pre1(t)->tile t; h2(t)->pre0 slice t.
// MODE0 flags: FN[role][g] = 64 words; word [slot*8+w] set to t+1 by wave w of wg slot
// after draining its own stores. Consumers min-poll the 8-word line of the producer wg.
template<int MODE>
__device__ __forceinline__ void rnn_body(
    int role, int g, int slot, int tid, int w, int lane, int cl, int kh, int lrow,
    const unsigned short* pre0, unsigned short* bufP, unsigned short* h1buf,
    const float* bias1,
    unsigned int* FCA0, unsigned int* FCA1, unsigned int* FCB, unsigned int* FCC,
    unsigned int* FLA, unsigned int* FLB, unsigned int* FLC,
    unsigned int* FNA, unsigned int* FNB, unsigned int* FNC,
    const short8* wf, unsigned short* hl, unsigned short* outl)
{
  constexpr bool FAST = (MODE < 2);
  int n0 = slot*128 + w*16;
  int olocal = w*128 + ((cl>>3)*8 + kh*4)*8 + (cl&7);    // j stride 8 shorts
  int khc = kh & 1;
  unsigned int* myFL = ((role == 0) ? FLA : (role == 1) ? FLB : FLC) + slot;
  unsigned int* myFN = ((role == 0) ? FNA : (role == 1) ? FNB : FNC) + slot*8 + w;

  for (int t = 0; t < Tn; ++t){
    unsigned short* hlb = (MODE == 0) ? hl + (t & 1)*8192 : hl;
    const char* lbase = (const char*)hlb;

    float pv[4] = {0.f,0.f,0.f,0.f};
    if (role == 0 && kh < 2){            // prefetch pre0 (plain cached; slice immutable here)
      const unsigned short* pp = pre0 + ((size_t)t*Bn + g*8 + kh*4)*Hn + n0 + cl;
#pragma unroll
      for (int j=0;j<4;j++) pv[j] = bf2f(pp[(size_t)j*Hn]);
    }
    bool staged = true;
    if constexpr (MODE == 0){
      // ---- per-wave detect (min over producer wg's 8 wave-flags) + slice stage ----
      if (role == 0){
        if (t > 0){
          wait8_nt(FNA + w*8, (unsigned)t);
          stage_pw(h1buf + ((size_t)(t+1)*8 + g)*8192 + w*1024, hlb + w*1024, lane);
        } else staged = false;
      } else if (role == 1){
        wait8_nt(FNA + w*8, (unsigned)(t+1));
        stage_pw(h1buf + ((size_t)(t+2)*8 + g)*8192 + w*1024, hlb + w*1024, lane);
      } else {
        const unsigned short* pA = h1buf + ((size_t)t*8 + g)*8192 + slot*1024
                                   + ((w*16+cl)>>3)*64 + khc*32 + (cl&7);   // pre1(t), own cols
        if (t > 0){
          wait8_nt2(FNC + w*8, (unsigned)t, FNB + slot*8, (unsigned)(t+1));
          stage_pw_pv(bufP + ((size_t)(t-1)*Bn + g*8)*Hn + w*1024, hlb + w*1024, lane, pA, pv);
        } else {
          staged = false;
          wait8_nt(FNB + slot*8, 1u);
          ld4_chunk<true>(pA, pv);
        }
      }
    } else {
      // ---- fallback modes: centralized tid0 wait + B1 + full stage (r12/r9/r4-proven) ----
      if (tid == 0){
        if (role == 0)      wait_one <FAST>(FCA0, FLA, 8u*(unsigned)t, (unsigned)t);
        else if (role == 1) wait_one <FAST>(FCA1, FLA, 8u*(unsigned)(t+1), (unsigned)(t+1));
        else                wait_dual<FAST>(FCB, FLB, 8u*(unsigned)(t+1), (unsigned)(t+1),
                                            FCC, FLC, 8u*(unsigned)t, (unsigned)t);
      }
      __syncthreads();                                             // B1
      if (role == 0){
        if (t > 0) stage_lin<FAST>(h1buf + ((size_t)(t+1)*8 + g)*8192, hlb, tid);
        else staged = false;
      } else if (role == 1){
        stage_lin<FAST>(h1buf + ((size_t)(t+2)*8 + g)*8192, hlb, tid);
      } else {
        if (kh < 2)
          ld4_chunk<FAST>(h1buf + ((size_t)t*8 + g)*8192 + slot*1024 + ((w*16+cl)>>3)*64 + kh*32 + (cl&7), pv);
        if (t > 0) stage_lin<FAST>(bufP + ((size_t)(t-1)*Bn + g*8)*Hn, hlb, tid);
        else staged = false;
      }
    }
    __syncthreads();                                               // B2 (tile staged)
    // ---- compute ----
    f32x4 acc = {0.f,0.f,0.f,0.f};
    if (staged) acc = mfma_tile(lbase, wf, lrow, kh);
    // ---- transpose to wave-local LDS, vector-store tile slice ----
    if (kh < 2){
      float bs = (role == 1) ? bias1[n0 + cl] : 0.f;
#pragma unroll
      for (int j=0;j<4;j++){
        float v = acc[j] + pv[j] + bs;
        if (role != 1) v = tanh_fast(v);
        outl[olocal + j*8] = f2bf(v);
      }
    }
    // same-wave cross-lane via LDS (ds ordering within wave), then vector store
    unsigned short* tile;
    if (role == 0)      tile = h1buf + ((size_t)(t+2)*8 + g)*8192;
    else if (role == 1) tile = h1buf + ((size_t)t*8 + g)*8192;
    else                tile = bufP + ((size_t)t*Bn + g*8)*Hn;
    if (lane < 16){
      u32x4 v = *(const u32x4*)(outl + w*128 + lane*8);
      st16<FAST>(tile + slot*1024 + (w*16 + lane)*8, v);
    }
    if constexpr (MODE == 0){
      // per-wave publish: drain own stores, lane0 sets this wave's flag word. No barrier.
      asm volatile("s_waitcnt vmcnt(0)" ::: "memory");
      if (lane == 0)
        asm volatile("global_store_dword %0, %1, off sc0" :: "v"(myFN), "v"((unsigned)(t+1)) : "memory");
    } else {
      asm volatile("s_waitcnt vmcnt(0)" ::: "memory");
      __syncthreads();                                             // B3
      if (tid == 0){
        if constexpr (MODE == 1){
          if (role == 0){ atom_inc(FCA0); atom_inc(FCA1); }
          else if (role == 1) atom_inc(FCB);
          else atom_inc(FCC);
        } else {
          asm volatile("global_store_dword %0, %1, off sc0 sc1" :: "v"(myFL), "v"((unsigned)(t+1)) : "memory");
        }
      }
    }
  }
}

__launch_bounds__(512, 2)
__global__ void rnn_fused(const unsigned short* __restrict__ pre0_ro,
                          unsigned short* __restrict__ bufP,
                          unsigned short* __restrict__ h1buf,
                          const float* __restrict__ Whh0,
                          const float* __restrict__ Wih1,
                          const float* __restrict__ Whh1,
                          const float* __restrict__ bias1,
                          unsigned int* ctrs)
{
  __shared__ __align__(16) unsigned short hl[16384];   // 2 x 16KB staged tile (chunk order)
  __shared__ __align__(16) unsigned short outl[1024];  // 2KB, wave-private transpose
  __shared__ int s_mode;
  int bx = blockIdx.x;
  int g = bx & 7;
  int sub = bx >> 3;
  int role = sub >> 3, slot = sub & 7;
  int tid = threadIdx.x, lane = tid & 63, w = tid >> 6;
  int n0 = slot*128 + w*16;
  int cl = lane & 15, kh = lane >> 4, lrow = cl & 7;
  unsigned int* FLA = ctrs + (0*8 + g)*32;   // MALL flag lines (8 words each)
  unsigned int* FLB = ctrs + (1*8 + g)*32;
  unsigned int* FLC = ctrs + (2*8 + g)*32;
  unsigned int* arrive1 = ctrs + 768;
  unsigned int* badAT   = ctrs + 772;
  unsigned int* arrive2 = ctrs + 776;
  unsigned int* badNT   = ctrs + 780;
  unsigned int* arrive3 = ctrs + 784;
  unsigned int* FCA0 = ctrs + 1536 + (0*8 + g)*32;  // MODE1 counters (128B-spaced)
  unsigned int* FCB  = ctrs + 1536 + (1*8 + g)*32;
  unsigned int* FCC  = ctrs + 1536 + (2*8 + g)*32;
  unsigned int* FCA1 = ctrs + 1536 + (3*8 + g)*32;
  unsigned int* FNA = ctrs + 2560 + (0*8 + g)*64;   // MODE0 per-(slot,wave) flags, 64 words
  unsigned int* FNB = ctrs + 2560 + (1*8 + g)*64;
  unsigned int* FNC = ctrs + 2560 + (2*8 + g)*64;

  // ---- one-time self-tests: NT sequence, then ATOM sequence; consensus via bad flags ----
  if (tid == 0){
    int xcc;
    asm volatile("s_getreg_b32 %0, hwreg(HW_REG_XCC_ID)" : "=s"(xcc));
    unsigned int* atw = ctrs + 1024 + g*32;  unsigned int* atarmed = atw + 16;
    unsigned int* ntw = ctrs + 1280 + g*32;  unsigned int* ntarmed = ntw + 16;
    if (xcc != g){
      __hip_atomic_fetch_or(badNT, 1u, __ATOMIC_RELAXED, __HIP_MEMORY_SCOPE_AGENT);
      __hip_atomic_fetch_or(badAT, 1u, __ATOMIC_RELAXED, __HIP_MEMORY_SCOPE_AGENT);
    }
    unsigned pr = ld1_nt(ntw) + ld1_nt(ntarmed);   // prime NT lines (stale-L1 hazard probe)
    asm volatile("" :: "v"(pr));
    __hip_atomic_fetch_add(arrive1, 1u, __ATOMIC_ACQ_REL, __HIP_MEMORY_SCOPE_AGENT);
    int t1 = 0;
    for (int i = 0; i < (1 << 20); ++i){
      if (__hip_atomic_load(arrive1, __ATOMIC_ACQUIRE, __HIP_MEMORY_SCOPE_AGENT) >= 192u){ t1 = 1; break; }
      __builtin_amdgcn_s_sleep(2);
    }
    if (!t1){
      __hip_atomic_fetch_or(badNT, 1u, __ATOMIC_RELAXED, __HIP_MEMORY_SCOPE_AGENT);
      __hip_atomic_fetch_or(badAT, 1u, __ATOMIC_RELAXED, __HIP_MEMORY_SCOPE_AGENT);
    }
    unsigned magicN = 0xBEEF0000u | (unsigned)g;
    if (sub == 0){
      asm volatile("global_store_dword %0, %1, off sc0\n\t"
                   "s_waitcnt vmcnt(0)\n\t"
                   "global_store_dword %2, %3, off sc0"
                   :: "v"(ntw), "v"(magicN), "v"(ntarmed), "v"(1u) : "memory");
    }
    int okN = 0;
    for (int i = 0; i < (1 << 14); ++i){
      if (ld1_nt(ntarmed) == 1u){ okN = (ld1_nt(ntw) == magicN); break; }
      if (i > 8) __builtin_amdgcn_s_sleep(1);
    }
    if (!okN) __hip_atomic_fetch_or(badNT, 1u, __ATOMIC_RELAXED, __HIP_MEMORY_SCOPE_AGENT);
    __hip_atomic_fetch_add(arrive2, 1u, __ATOMIC_ACQ_REL, __HIP_MEMORY_SCOPE_AGENT);
    int t2 = 0;
    for (int i = 0; i < (1 << 20); ++i){
      if (__hip_atomic_load(arrive2, __ATOMIC_ACQUIRE, __HIP_MEMORY_SCOPE_AGENT) >= 192u){ t2 = 1; break; }
      __builtin_amdgcn_s_sleep(2);
    }
    if (!t2){
      __hip_atomic_fetch_or(badNT, 1u, __ATOMIC_RELAXED, __HIP_MEMORY_SCOPE_AGENT);
      __hip_atomic_fetch_or(badAT, 1u, __ATOMIC_RELAXED, __HIP_MEMORY_SCOPE_AGENT);
    }
    unsigned magicA = 0xCAFE0000u | (unsigned)g;
    if (sub == 0){
      asm volatile("global_store_dword %0, %1, off sc0\n\t"
                   "s_waitcnt vmcnt(0)" :: "v"(atw), "v"(magicA) : "memory");
      atom_inc(atarmed);
    }
    int okA = 0;
    for (int i = 0; i < (1 << 15); ++i){
      if (atom_poll(atarmed) >= 1u){ okA = (ld1_sc0(atw) == magicA); break; }
      if (i > 16) __builtin_amdgcn_s_sleep(1);
    }
    if (!okA) __hip_atomic_fetch_or(badAT, 1u, __ATOMIC_RELAXED, __HIP_MEMORY_SCOPE_AGENT);
    __hip_atomic_fetch_add(arrive3, 1u, __ATOMIC_ACQ_REL, __HIP_MEMORY_SCOPE_AGENT);
    int t3 = 0;
    for (int i = 0; i < (1 << 20); ++i){
      if (__hip_atomic_load(arrive3, __ATOMIC_ACQUIRE, __HIP_MEMORY_SCOPE_AGENT) >= 192u){ t3 = 1; break; }
      __builtin_amdgcn_s_sleep(2);
    }
    unsigned bN = __hip_atomic_load(badNT, __ATOMIC_ACQUIRE, __HIP_MEMORY_SCOPE_AGENT);
    unsigned bA = __hip_atomic_load(badAT, __ATOMIC_ACQUIRE, __HIP_MEMORY_SCOPE_AGENT);
    s_mode = (!t3) ? 2 : (bN == 0u ? 0 : (bA == 0u ? 1 : 2));
  }
  __syncthreads();
  const int mode = s_mode;

  // Resident weight slice as MFMA B-fragments: lane holds W[n0+cl][kk*32+kh*8+0..7]
  const float* Wmat = (role == 0) ? Whh0 : (role == 1) ? Wih1 : Whh1;
  short8 wf[32];
  {
    const float* wr = Wmat + (size_t)(n0 + cl)*Hn + kh*8;
#pragma unroll
    for (int kk = 0; kk < 32; ++kk){
      float4 a = *(const float4*)(wr + kk*32);
      float4 b = *(const float4*)(wr + kk*32 + 4);
      short8 v;
      v[0]=(short)f2bf(a.x); v[1]=(short)f2bf(a.y); v[2]=(short)f2bf(a.z); v[3]=(short)f2bf(a.w);
      v[4]=(short)f2bf(b.x); v[5]=(short)f2bf(b.y); v[6]=(short)f2bf(b.z); v[7]=(short)f2bf(b.w);
      wf[kk] = v;
    }
  }

  if (mode == 0)
    rnn_body<0>(role, g, slot, tid, w, lane, cl, kh, lrow, pre0_ro, bufP, h1buf,
                bias1, FCA0, FCA1, FCB, FCC, FLA, FLB, FLC, FNA, FNB, FNC, wf, hl, outl);
  else if (mode == 1)
    rnn_body<1>(role, g, slot, tid, w, lane, cl, kh, lrow, pre0_ro, bufP, h1buf,
                bias1, FCA0, FCA1, FCB, FCC, FLA, FLB, FLC, FNA, FNB, FNC, wf, hl, outl);
  else
    rnn_body<2>(role, g, slot, tid, w, lane, cl, kh, lrow, pre0_ro, bufP, h1buf,
                bias1, FCA0, FCA1, FCB, FCC, FLA, FLB, FLC, FNA, FNB, FNC, wf, hl, outl);
}

// ---------------- FC head: out[b][o] = h2[b][T-1][:] . Wfc[o][:] + bfc[o] ----------------
__global__ void fc_k(const unsigned short* __restrict__ bufP,
                     const float* __restrict__ Wfc, const float* __restrict__ bfc,
                     float* __restrict__ out)
{
  int gw = (blockIdx.x * blockDim.x + threadIdx.x) >> 6;
  int lane = threadIdx.x & 63;
  int b = gw >> 7, o = gw & 127;
  // h2(T-1) lives in pre0 slice T-1, group tile (b>>3), chunk-ordered
  const unsigned short* tile = bufP + ((size_t)(Tn-1)*Bn + (b & ~7))*Hn;
  int r = b & 7;
  const float* wr = Wfc + (size_t)o*Hn;
  float s = 0.f;
  for (int k = lane; k < Hn; k += 64)
    s += bf2f(tile[((k>>3)*8 + r)*8 + (k&7)]) * wr[k];
#pragma unroll
  for (int off = 32; off > 0; off >>= 1) s += __shfl_down(s, off, 64);
  if (lane == 0) out[b*OUTn + o] = s + bfc[o];
}

// ---------------- host ----------------
extern "C" void kernel_launch(void* const* d_in, const int* in_sizes, int n_in,
                              void* d_out, int out_size, void* d_ws, size_t ws_size,
                              hipStream_t stream)
{
  const float* x    = (const float*)d_in[0];
  const float* Wih0 = (const float*)d_in[1];
  const float* Whh0 = (const float*)d_in[2];
  const float* bih0 = (const float*)d_in[3];
  const float* bhh0 = (const float*)d_in[4];
  const float* Wih1 = (const float*)d_in[5];
  const float* Whh1 = (const float*)d_in[6];
  const float* bih1 = (const float*)d_in[7];
  const float* bhh1 = (const float*)d_in[8];
  const float* Wfc  = (const float*)d_in[9];
  const float* bfc  = (const float*)d_in[10];
  float* out = (float*)d_out;

  // workspace (bf16 elements)
  unsigned short* bufP  = (unsigned short*)d_ws;                    // pre0 [T][B][H]; h2 aliases slices
  unsigned short* h1buf = bufP  + (size_t)Bn*Tn*Hn;                 // (T+2)*8 chunk-ordered 16KB tiles
  unsigned short* wih0b = h1buf + (size_t)(Tn+2)*8*8192;            // 1MiB
  float* bias0 = (float*)(wih0b + (size_t)Hn*DINn);
  float* bias1 = bias0 + Hn;
  unsigned int* ctrs = (unsigned int*)(bias1 + Hn);                 // 4096 uints

  hipMemsetAsync(ctrs, 0, 4096*sizeof(unsigned int), stream);

  cvt_bf16x8<<<256, 256, 0, stream>>>(Wih0, wih0b, (long long)Hn*DINn/8);
  bias_combine<<<4, 256, 0, stream>>>(bih0, bhh0, bias0, bih1, bhh1, bias1);

  // pre0 = x @ Wih0^T + bias0, written as [T][B][H]
  dim3 g1(Hn/128, (Bn*Tn)/128);
  gemm_pre0<<<g1, 256, 0, stream>>>(x, wih0b, bias0, bufP, Hn, DINn);

  // fused 3-stage pipeline (MODE0: per-wave detect + per-wave publish; ATOM/MALL fallback)
  rnn_fused<<<192, 512, 0, stream>>>(bufP, bufP, h1buf, Whh0, Wih1, Whh1, bias1, ctrs);

  // FC head from h2(T-1) (aliased into pre0 slice T-1)
  fc_k<<<2048, 256, 0, stream>>>(bufP, Wfc, bfc, out);
}